// Round 16
// baseline (305.048 us; speedup 1.0000x reference)
//
#include <hip/hip_runtime.h>
#include <hip/hip_fp16.h>

#define IN_F 512
#define OH   512   // OUT*H
#define NH   8     // heads

typedef _Float16 half_t;
typedef __attribute__((ext_vector_type(8))) _Float16 f16x8;
typedef __attribute__((ext_vector_type(4))) float    f32x4;

#define GLOBAL_AS const __attribute__((address_space(1))) void
#define LDS_AS    __attribute__((address_space(3))) void

__device__ static inline void gload_lds16(const void* g, void* l) {
  __builtin_amdgcn_global_load_lds((GLOBAL_AS*)g, (LDS_AS*)l, 16, 0, 0);
}

// ---------------------------------------------------------------------------
// fused prep: cast W f32->f16 [0,nbW) + degree histogram [nbW,nbW+nbH) +
// zero el/er [nbW+nbH, ...).  (deg and the scan ticket are zeroed by a
// preceding memset.)
// ---------------------------------------------------------------------------
__global__ __launch_bounds__(256) void k_prep(const float* __restrict__ W,
                                              half_t* __restrict__ Wh, int nWe,
                                              const int* __restrict__ row,
                                              int* __restrict__ deg, int E,
                                              float* __restrict__ elr, int nZ4,
                                              int nbW, int nbH) {
  int b = blockIdx.x;
  if (b < nbW) {
    int i = (b * 256 + threadIdx.x) * 8;
    if (i >= nWe) return;
    float4 a = *(const float4*)(W + i);
    float4 c = *(const float4*)(W + i + 4);
    f16x8 h;
    h[0] = (half_t)a.x; h[1] = (half_t)a.y; h[2] = (half_t)a.z; h[3] = (half_t)a.w;
    h[4] = (half_t)c.x; h[5] = (half_t)c.y; h[6] = (half_t)c.z; h[7] = (half_t)c.w;
    *(f16x8*)(Wh + i) = h;
  } else if (b < nbW + nbH) {
    int e = (b - nbW) * 256 + threadIdx.x;
    if (e < E) atomicAdd(&deg[row[e]], 1);
  } else {
    int i = (b - nbW - nbH) * 256 + threadIdx.x;   // float4 index
    if (i < nZ4) ((float4*)elr)[i] = make_float4(0.f, 0.f, 0.f, 0.f);
  }
}

// ---------------------------------------------------------------------------
// Single-launch CSR scan: per-block local exclusive scan; the LAST block to
// finish (atomic ticket on done = &deg[N], pre-zeroed) computes the block-
// offset prefix and applies it grid-wide to off + cursor.  Correct without
// dispatch-order assumptions: every block fences its off/sums stores before
// taking a ticket, so the ticket==nb-1 block sees all of them.
// ---------------------------------------------------------------------------
#define SCAN_B 1024
__global__ __launch_bounds__(SCAN_B) void k_scan(const int* __restrict__ deg,
                                                 int* __restrict__ off,
                                                 int* __restrict__ cursor,
                                                 int* __restrict__ sums,
                                                 int* __restrict__ done,
                                                 int nb, int N, int E) {
  __shared__ int s[SCAN_B];
  __shared__ int boff[64];
  __shared__ int ticket;
  int tid = threadIdx.x;
  int g = blockIdx.x * SCAN_B + tid;
  int v = (g < N) ? deg[g] : 0;
  s[tid] = v;
  __syncthreads();
  for (int o = 1; o < SCAN_B; o <<= 1) {
    int t = (tid >= o) ? s[tid - o] : 0;
    __syncthreads();
    s[tid] += t;
    __syncthreads();
  }
  if (g < N) off[g] = s[tid] - v;            // exclusive prefix within block
  if (tid == SCAN_B - 1) sums[blockIdx.x] = s[tid];
  __threadfence();                           // publish off + sums
  if (tid == 0) ticket = atomicAdd(done, 1);
  __syncthreads();
  if (ticket != nb - 1) return;

  // ---- finalizer (last block): all other blocks' stores are visible
  __threadfence();
  if (tid == 0) {
    int run = 0;
    for (int b = 0; b < nb; b++) { boff[b] = run; run += sums[b]; }
  }
  __syncthreads();
  for (int i = tid; i < N; i += SCAN_B) {
    int v2 = off[i] + boff[i >> 10];
    off[i] = v2;
    cursor[i] = v2;
  }
  if (tid == 0) off[N] = E;
}

// ---------------------------------------------------------------------------
// Mega kernel: blocks [0, nwgG) = MFMA f16 GEMM v7b (best measured);
// blocks [nwgG, ...) = CSR fill -- slots into the GEMM's second-round idle
// CUs.  GEMM: full-width 128x512 tile, 8 waves, 96KB LDS double-buffer,
// global_load_lds + granule-XOR swizzle (rule #21), counted vmcnt(6) ledger,
// raw s_barrier, s_setprio around the MFMA cluster (T5).
// Epilogue: Zh write + fused per-head el/er atomic partials.
// ---------------------------------------------------------------------------
__global__ __launch_bounds__(512) void k_mega(const float* __restrict__ X,
                                              const half_t* __restrict__ Wh,
                                              const float* __restrict__ bias,
                                              const float* __restrict__ al,
                                              const float* __restrict__ ar,
                                              half_t* __restrict__ Zh,
                                              float* __restrict__ el,
                                              float* __restrict__ er,
                                              int N, int nwgG,
                                              const int* __restrict__ row,
                                              const int* __restrict__ col,
                                              int* __restrict__ cursor,
                                              int* __restrict__ colS, int E) {
  __shared__ float  As[2][128 * 32];   // 2 x 16 KB, linear
  __shared__ half_t Bs[2][512 * 32];   // 2 x 32 KB, linear

  if (blockIdx.x >= nwgG) {
    // ---------------- CSR fill part ----------------
    int e = (blockIdx.x - nwgG) * 512 + threadIdx.x;
    if (e < E) {
      int r = row[e];
      int p = atomicAdd(&cursor[r], 1);
      colS[p] = col[e];
    }
    return;
  }

  // ---------------- GEMM part (v7b) ----------------
  const int tid  = threadIdx.x;
  const int lane = tid & 63;
  const int wid  = tid >> 6;           // 0..7
  const int wr = wid >> 2, wc = wid & 3;

  // bijective XCD swizzle (m204)
  int orig = blockIdx.x;
  int xcd = orig & 7;
  int q = nwgG >> 3, r = nwgG & 7;
  int start = (xcd < r) ? xcd * (q + 1) : r * (q + 1) + (xcd - r) * q;
  int work = start + (orig >> 3);
  const int n0 = work * 128;

  const int rl = lane & 15;
  const int hi16 = lane >> 4;

  // ---- staging maps (kt-invariant) ----
  int a_row[2], a_goff[2];
#pragma unroll
  for (int c = 0; c < 2; c++) {
    int off = c * 8192 + wid * 1024 + lane * 16;
    int rrow = off >> 7;                 // 0..127 (128B per f32 row)
    int sg = (off >> 4) & 7;             // LDS granule in row
    a_row[c]  = rrow;
    a_goff[c] = (sg ^ (rrow & 7)) << 2;  // source f32 offset in row
  }
  int b_row[4], b_goff[4];
#pragma unroll
  for (int c = 0; c < 4; c++) {
    int off = c * 8192 + wid * 1024 + lane * 16;
    int jr = off >> 6;                   // 0..511 (64B per f16 row)
    int g  = (off >> 4) & 3;
    b_row[c]  = jr;
    b_goff[c] = (g ^ ((jr >> 1) & 3)) << 3;  // source half offset in row
  }

#define STAGE(BUF, KT)                                                          \
  do {                                                                          \
    _Pragma("unroll")                                                           \
    for (int c = 0; c < 2; c++) {                                               \
      int an = n0 + a_row[c]; if (an >= N) an = N - 1;                          \
      const float* g = X + (size_t)an * IN_F + (KT) + a_goff[c];                \
      gload_lds16(g, (char*)&As[BUF][0] + c * 8192 + wid * 1024);               \
    }                                                                           \
    _Pragma("unroll")                                                           \
    for (int c = 0; c < 4; c++) {                                               \
      const half_t* g = Wh + (size_t)b_row[c] * IN_F + (KT) + b_goff[c];        \
      gload_lds16(g, (char*)&Bs[BUF][0] + c * 8192 + wid * 1024);               \
    }                                                                           \
  } while (0)

  f32x4 acc[4][8] = {};

  STAGE(0, 0);

#pragma unroll
  for (int ki = 0; ki < 16; ki++) {
    const int cur = ki & 1;
    if (ki < 15) {
      STAGE(cur ^ 1, (ki + 1) * 32);
      asm volatile("s_waitcnt vmcnt(6)" ::: "memory");   // stage ki complete
    } else {
      asm volatile("s_waitcnt vmcnt(0)" ::: "memory");
    }
    __builtin_amdgcn_sched_barrier(0);
    __builtin_amdgcn_s_barrier();

    // ---- fragments (swizzled ds_read) ----
    f16x8 af[4], bf[8];
#pragma unroll
    for (int m = 0; m < 4; m++) {
      int rr = wr * 64 + m * 16 + rl;
      int r7 = rr & 7;
      const char* base = (const char*)&As[cur][0] + rr * 128;
      f32x4 lo = *(const f32x4*)(base + (((hi16 * 2) ^ r7) << 4));
      f32x4 hi = *(const f32x4*)(base + (((hi16 * 2 + 1) ^ r7) << 4));
      f16x8 a;
#pragma unroll
      for (int u = 0; u < 4; u++) { a[u] = (half_t)lo[u]; a[u + 4] = (half_t)hi[u]; }
      af[m] = a;
    }
#pragma unroll
    for (int n = 0; n < 8; n++) {
      int jr = wc * 128 + n * 16 + rl;
      bf[n] = *(const f16x8*)((const char*)&Bs[cur][0] + jr * 64 +
                              ((hi16 ^ ((jr >> 1) & 3)) << 4));
    }
    __builtin_amdgcn_s_setprio(1);
#pragma unroll
    for (int m = 0; m < 4; m++)
#pragma unroll
      for (int n = 0; n < 8; n++)
        acc[m][n] = __builtin_amdgcn_mfma_f32_16x16x32_f16(af[m], bf[n], acc[m][n], 0, 0, 0);
    __builtin_amdgcn_s_setprio(0);

    __builtin_amdgcn_s_barrier();   // all reads of buf[cur] done before restage
  }
#undef STAGE

  // ---- epilogue: Zh write + per-head el/er partials ----
  float bv[8], av[8], rv[8];
#pragma unroll
  for (int n = 0; n < 8; n++) {
    int j = wc * 128 + n * 16 + rl;
    bv[n] = bias[j]; av[n] = al[j]; rv[n] = ar[j];
  }

  float partl[4][4], partr[4][4];
#pragma unroll
  for (int m = 0; m < 4; m++)
#pragma unroll
    for (int qq = 0; qq < 4; qq++) { partl[m][qq] = 0.f; partr[m][qq] = 0.f; }

#pragma unroll
  for (int n = 0; n < 8; n++) {
    int j = wc * 128 + n * 16 + rl;
#pragma unroll
    for (int m = 0; m < 4; m++) {
      int rbase = n0 + wr * 64 + m * 16 + hi16 * 4;
#pragma unroll
      for (int qq = 0; qq < 4; qq++) {
        float v = acc[m][n][qq] + bv[n];
        int nrow = rbase + qq;
        if (nrow < N) Zh[(size_t)nrow * OH + j] = (half_t)v;
        partl[m][qq] = fmaf(v, av[n], partl[m][qq]);
        partr[m][qq] = fmaf(v, rv[n], partr[m][qq]);
      }
    }
  }
  const int h = rl & 7;
#pragma unroll
  for (int m = 0; m < 4; m++) {
#pragma unroll
    for (int qq = 0; qq < 4; qq++) {
      float pl = partl[m][qq], pr = partr[m][qq];
      pl += __shfl_xor(pl, 8);    // fold rl and rl+8 (same head)
      pr += __shfl_xor(pr, 8);
      if (rl < 8) {
        int nrow = n0 + wr * 64 + m * 16 + hi16 * 4 + qq;
        if (nrow < N) {
          atomicAdd(&el[(size_t)nrow * NH + h], pl);
          atomicAdd(&er[(size_t)nrow * NH + h], pr);
        }
      }
    }
  }
}

// ---------------------------------------------------------------------------
// Fused edge-softmax + aggregation (NT store for out, NT load for colS)
// ---------------------------------------------------------------------------
__global__ __launch_bounds__(256) void k_attagg(const half_t* __restrict__ Zh,
                                                const float* __restrict__ el,
                                                const float* __restrict__ er,
                                                const int* __restrict__ off,
                                                const int* __restrict__ colS,
                                                float* __restrict__ out, int N) {
  __shared__ float wts[4][64][NH];   // 8 KB
  __shared__ int   cls[4][64];       // 1 KB
  int wid = threadIdx.x >> 6, lane = threadIdx.x & 63;
  int i = blockIdx.x * 4 + wid;
  if (i >= N) return;
  int s = off[i], t = off[i + 1];
  int deg = t - s;

  float eli[8];
  {
    const float4* e4 = (const float4*)(el + (size_t)i * NH);
    float4 a = e4[0], b = e4[1];
    eli[0] = a.x; eli[1] = a.y; eli[2] = a.z; eli[3] = a.w;
    eli[4] = b.x; eli[5] = b.y; eli[6] = b.z; eli[7] = b.w;
  }

  float m[8], ehs[8];
  int csave = 0;
#pragma unroll
  for (int h = 0; h < 8; h++) m[h] = -1e30f;
  for (int p = s + lane; p < t; p += 64) {
    int c = __builtin_nontemporal_load(&colS[p]);
    csave = c;
    const float4* e4 = (const float4*)(er + (size_t)c * NH);
    float4 ea = e4[0], eb = e4[1];
    float ev[8] = {ea.x, ea.y, ea.z, ea.w, eb.x, eb.y, eb.z, eb.w};
#pragma unroll
    for (int h = 0; h < 8; h++) {
      float eh = eli[h] + ev[h];
      eh = (eh > 0.f) ? eh : 0.01f * eh;
      ehs[h] = eh;
      m[h] = fmaxf(m[h], eh);
    }
  }
#pragma unroll
  for (int st = 1; st < 64; st <<= 1)
#pragma unroll
    for (int h = 0; h < 8; h++) m[h] = fmaxf(m[h], __shfl_xor(m[h], st));

  float acc[8], den[8];
#pragma unroll
  for (int h = 0; h < 8; h++) { acc[h] = 0.f; den[h] = 0.f; }

  for (int base = s; base < t; base += 64) {
    int p = base + lane;
    if (p < t) {
      int c;
      float eh[8];
      if (deg <= 64) {
        c = csave;
#pragma unroll
        for (int h = 0; h < 8; h++) eh[h] = ehs[h];
      } else {
        c = __builtin_nontemporal_load(&colS[p]);
        const float4* e4 = (const float4*)(er + (size_t)c * NH);
        float4 ea = e4[0], eb = e4[1];
        float ev[8] = {ea.x, ea.y, ea.z, ea.w, eb.x, eb.y, eb.z, eb.w};
#pragma unroll
        for (int h = 0; h < 8; h++) {
          float e2 = eli[h] + ev[h];
          eh[h] = (e2 > 0.f) ? e2 : 0.01f * e2;
        }
      }
      cls[wid][lane] = c;
#pragma unroll
      for (int h = 0; h < 8; h++) {
        float pr = __expf(eh[h] - m[h]);
        den[h] += pr;
        wts[wid][lane][h] = pr;
      }
    }
    int cnt = t - base; if (cnt > 64) cnt = 64;

    int e = 0;
    for (; e + 4 <= cnt; e += 4) {
      int c0 = cls[wid][e + 0], c1 = cls[wid][e + 1];
      int c2 = cls[wid][e + 2], c3 = cls[wid][e + 3];
      f16x8 z0 = *(const f16x8*)(Zh + (size_t)c0 * OH + lane * 8);
      f16x8 z1 = *(const f16x8*)(Zh + (size_t)c1 * OH + lane * 8);
      f16x8 z2 = *(const f16x8*)(Zh + (size_t)c2 * OH + lane * 8);
      f16x8 z3 = *(const f16x8*)(Zh + (size_t)c3 * OH + lane * 8);
      const float* w0 = &wts[wid][e + 0][0];
      const float* w1 = &wts[wid][e + 1][0];
      const float* w2 = &wts[wid][e + 2][0];
      const float* w3 = &wts[wid][e + 3][0];
#pragma unroll
      for (int h = 0; h < 8; h++) {
        acc[h] = fmaf(w0[h], (float)z0[h], acc[h]);
        acc[h] = fmaf(w1[h], (float)z1[h], acc[h]);
        acc[h] = fmaf(w2[h], (float)z2[h], acc[h]);
        acc[h] = fmaf(w3[h], (float)z3[h], acc[h]);
      }
    }
    for (; e < cnt; e++) {
      int c = cls[wid][e];
      f16x8 z = *(const f16x8*)(Zh + (size_t)c * OH + lane * 8);
      const float* w = &wts[wid][e][0];
#pragma unroll
      for (int h = 0; h < 8; h++) acc[h] = fmaf(w[h], (float)z[h], acc[h]);
    }
  }

#pragma unroll
  for (int st = 1; st < 64; st <<= 1)
#pragma unroll
    for (int h = 0; h < 8; h++) den[h] += __shfl_xor(den[h], st);

  f32x4 o0, o1;
  o0[0] = acc[0] / den[0]; o0[1] = acc[1] / den[1];
  o0[2] = acc[2] / den[2]; o0[3] = acc[3] / den[3];
  o1[0] = acc[4] / den[4]; o1[1] = acc[5] / den[5];
  o1[2] = acc[6] / den[6]; o1[3] = acc[7] / den[7];
  __builtin_nontemporal_store(o0, (f32x4*)(out + (size_t)i * OH + lane * 8));
  __builtin_nontemporal_store(o1, (f32x4*)(out + (size_t)i * OH + lane * 8 + 4));
}

// ---------------------------------------------------------------------------
extern "C" void kernel_launch(void* const* d_in, const int* in_sizes, int n_in,
                              void* d_out, int out_size, void* d_ws, size_t ws_size,
                              hipStream_t stream) {
  const float* X    = (const float*)d_in[0];
  const float* W    = (const float*)d_in[1];
  const float* bias = (const float*)d_in[2];
  const float* a_l  = (const float*)d_in[3];
  const float* a_r  = (const float*)d_in[4];
  const int*   row  = (const int*)d_in[5];
  const int*   col  = (const int*)d_in[6];
  float* out = (float*)d_out;

  const int N = in_sizes[0] / IN_F;   // 50000
  const int E = in_sizes[5];          // 850000
  const int nWe = OH * IN_F;

  auto align_up = [](size_t v) { return (v + 255) & ~(size_t)255; };
  char* p = (char*)d_ws;
  half_t* Wh    = (half_t*)p; p += align_up((size_t)nWe * 2);
  half_t* Zh    = (half_t*)p; p += align_up((size_t)N * OH * 2);
  float* el     = (float*)p;  p += (size_t)N * NH * 4;        // el/er contiguous
  float* er     = (float*)p;  p += align_up((size_t)N * NH * 4);
  int*   deg    = (int*)p;    p += align_up((size_t)(N + 64) * 4);  // +ticket
  int*   off    = (int*)p;    p += align_up((size_t)(N + 1) * 4);
  int*   cursor = (int*)p;    p += align_up((size_t)N * 4);
  int*   sums   = (int*)p;    p += align_up((size_t)64 * 4);
  int*   colS   = (int*)p;    p += align_up((size_t)E * 4);
  int*   done   = deg + N;    // zeroed together with deg
  (void)ws_size; (void)n_in; (void)out_size;

  const int nb = (N + SCAN_B - 1) / SCAN_B;

  // deg + ticket must be zero before prep's histogram / the scan
  hipMemsetAsync(deg, 0, (size_t)(N + 64) * 4, stream);

  // prep: cast W + degree histogram + zero el/er
  const int nbW = (nWe / 8 + 255) / 256;
  const int nbH = (E + 255) / 256;
  const int nZ4 = 2 * N * NH / 4;
  const int nbZ = (nZ4 + 255) / 256;
  hipLaunchKernelGGL(k_prep, dim3(nbW + nbH + nbZ), dim3(256), 0, stream,
                     W, Wh, nWe, row, deg, E, el, nZ4, nbW, nbH);

  // single-launch CSR scan (local scans + last-block finalizer)
  hipLaunchKernelGGL(k_scan, dim3(nb), dim3(SCAN_B), 0, stream,
                     deg, off, cursor, sums, done, nb, N, E);

  // mega: GEMM (v7b + setprio) + CSR fill in one launch
  const int nwgG = (N + 127) / 128;              // 391 GEMM blocks
  const int nbF  = (E + 511) / 512;              // fill blocks
  hipLaunchKernelGGL(k_mega, dim3(nwgG + nbF), dim3(512), 0, stream,
                     X, Wh, bias, a_l, a_r, Zh, el, er, N, nwgG,
                     row, col, cursor, colS, E);

  // fused softmax + aggregation
  hipLaunchKernelGGL(k_attagg, dim3((N + 3) / 4), dim3(256), 0, stream,
                     Zh, el, er, off, colS, out, N);
}

// Round 17
// 279.394 us; speedup vs baseline: 1.0918x; 1.0918x over previous
//
#include <hip/hip_runtime.h>
#include <hip/hip_fp16.h>

#define IN_F 512
#define OH   512   // OUT*H
#define NH   8     // heads

typedef _Float16 half_t;
typedef __attribute__((ext_vector_type(8))) _Float16 f16x8;
typedef __attribute__((ext_vector_type(4))) float    f32x4;

#define GLOBAL_AS const __attribute__((address_space(1))) void
#define LDS_AS    __attribute__((address_space(3))) void

__device__ static inline void gload_lds16(const void* g, void* l) {
  __builtin_amdgcn_global_load_lds((GLOBAL_AS*)g, (LDS_AS*)l, 16, 0, 0);
}

// ---------------------------------------------------------------------------
// fused prep: cast W f32->f16 [0,nbW) + degree histogram [nbW,nbW+nbH) +
// zero el/er [nbW+nbH, ...).  (deg is zeroed by a preceding memset.)
// ---------------------------------------------------------------------------
__global__ __launch_bounds__(256) void k_prep(const float* __restrict__ W,
                                              half_t* __restrict__ Wh, int nWe,
                                              const int* __restrict__ row,
                                              int* __restrict__ deg, int E,
                                              float* __restrict__ elr, int nZ4,
                                              int nbW, int nbH) {
  int b = blockIdx.x;
  if (b < nbW) {
    int i = (b * 256 + threadIdx.x) * 8;
    if (i >= nWe) return;
    float4 a = *(const float4*)(W + i);
    float4 c = *(const float4*)(W + i + 4);
    f16x8 h;
    h[0] = (half_t)a.x; h[1] = (half_t)a.y; h[2] = (half_t)a.z; h[3] = (half_t)a.w;
    h[4] = (half_t)c.x; h[5] = (half_t)c.y; h[6] = (half_t)c.z; h[7] = (half_t)c.w;
    *(f16x8*)(Wh + i) = h;
  } else if (b < nbW + nbH) {
    int e = (b - nbW) * 256 + threadIdx.x;
    if (e < E) atomicAdd(&deg[row[e]], 1);
  } else {
    int i = (b - nbW - nbH) * 256 + threadIdx.x;   // float4 index
    if (i < nZ4) ((float4*)elr)[i] = make_float4(0.f, 0.f, 0.f, 0.f);
  }
}

// ---------------------------------------------------------------------------
// Mega kernel: blocks [0, nwgG) = MFMA f16 GEMM v7b (best measured);
// blocks [nwgG, ...) = CSR fill (random scatter) -- slots into the GEMM's
// second-round idle CUs, so its ~15us hides inside the GEMM makespan.
//
// GEMM: full-width 128x512 tile, 8 waves, 96KB LDS double-buffer,
// global_load_lds with granule-XOR swizzle (source+read side, rule #21),
// counted vmcnt(6) ledger, raw s_barrier.  X read ONCE per row-panel.
// Epilogue: Zh write + fused per-head el/er atomic partials.
// ---------------------------------------------------------------------------
__global__ __launch_bounds__(512) void k_mega(const float* __restrict__ X,
                                              const half_t* __restrict__ Wh,
                                              const float* __restrict__ bias,
                                              const float* __restrict__ al,
                                              const float* __restrict__ ar,
                                              half_t* __restrict__ Zh,
                                              float* __restrict__ el,
                                              float* __restrict__ er,
                                              int N, int nwgG,
                                              const int* __restrict__ row,
                                              const int* __restrict__ col,
                                              int* __restrict__ cursor,
                                              int* __restrict__ colS, int E) {
  __shared__ float  As[2][128 * 32];   // 2 x 16 KB, linear
  __shared__ half_t Bs[2][512 * 32];   // 2 x 32 KB, linear

  if (blockIdx.x >= nwgG) {
    // ---------------- CSR fill part ----------------
    int e = (blockIdx.x - nwgG) * 512 + threadIdx.x;
    if (e < E) {
      int r = row[e];
      int p = atomicAdd(&cursor[r], 1);
      colS[p] = col[e];
    }
    return;
  }

  // ---------------- GEMM part (v7b verbatim) ----------------
  const int tid  = threadIdx.x;
  const int lane = tid & 63;
  const int wid  = tid >> 6;           // 0..7
  const int wr = wid >> 2, wc = wid & 3;

  // bijective XCD swizzle (m204)
  int orig = blockIdx.x;
  int xcd = orig & 7;
  int q = nwgG >> 3, r = nwgG & 7;
  int start = (xcd < r) ? xcd * (q + 1) : r * (q + 1) + (xcd - r) * q;
  int work = start + (orig >> 3);
  const int n0 = work * 128;

  const int rl = lane & 15;
  const int hi16 = lane >> 4;

  // ---- staging maps (kt-invariant) ----
  int a_row[2], a_goff[2];
#pragma unroll
  for (int c = 0; c < 2; c++) {
    int off = c * 8192 + wid * 1024 + lane * 16;
    int rrow = off >> 7;                 // 0..127 (128B per f32 row)
    int sg = (off >> 4) & 7;             // LDS granule in row
    a_row[c]  = rrow;
    a_goff[c] = (sg ^ (rrow & 7)) << 2;  // source f32 offset in row
  }
  int b_row[4], b_goff[4];
#pragma unroll
  for (int c = 0; c < 4; c++) {
    int off = c * 8192 + wid * 1024 + lane * 16;
    int jr = off >> 6;                   // 0..511 (64B per f16 row)
    int g  = (off >> 4) & 3;
    b_row[c]  = jr;
    b_goff[c] = (g ^ ((jr >> 1) & 3)) << 3;  // source half offset in row
  }

#define STAGE(BUF, KT)                                                          \
  do {                                                                          \
    _Pragma("unroll")                                                           \
    for (int c = 0; c < 2; c++) {                                               \
      int an = n0 + a_row[c]; if (an >= N) an = N - 1;                          \
      const float* g = X + (size_t)an * IN_F + (KT) + a_goff[c];                \
      gload_lds16(g, (char*)&As[BUF][0] + c * 8192 + wid * 1024);               \
    }                                                                           \
    _Pragma("unroll")                                                           \
    for (int c = 0; c < 4; c++) {                                               \
      const half_t* g = Wh + (size_t)b_row[c] * IN_F + (KT) + b_goff[c];        \
      gload_lds16(g, (char*)&Bs[BUF][0] + c * 8192 + wid * 1024);               \
    }                                                                           \
  } while (0)

  f32x4 acc[4][8] = {};

  STAGE(0, 0);

#pragma unroll
  for (int ki = 0; ki < 16; ki++) {
    const int cur = ki & 1;
    if (ki < 15) {
      STAGE(cur ^ 1, (ki + 1) * 32);
      asm volatile("s_waitcnt vmcnt(6)" ::: "memory");   // stage ki complete
    } else {
      asm volatile("s_waitcnt vmcnt(0)" ::: "memory");
    }
    __builtin_amdgcn_sched_barrier(0);
    __builtin_amdgcn_s_barrier();

    // ---- fragments (swizzled ds_read) ----
    f16x8 af[4], bf[8];
#pragma unroll
    for (int m = 0; m < 4; m++) {
      int rr = wr * 64 + m * 16 + rl;
      int r7 = rr & 7;
      const char* base = (const char*)&As[cur][0] + rr * 128;
      f32x4 lo = *(const f32x4*)(base + (((hi16 * 2) ^ r7) << 4));
      f32x4 hi = *(const f32x4*)(base + (((hi16 * 2 + 1) ^ r7) << 4));
      f16x8 a;
#pragma unroll
      for (int u = 0; u < 4; u++) { a[u] = (half_t)lo[u]; a[u + 4] = (half_t)hi[u]; }
      af[m] = a;
    }
#pragma unroll
    for (int n = 0; n < 8; n++) {
      int jr = wc * 128 + n * 16 + rl;
      bf[n] = *(const f16x8*)((const char*)&Bs[cur][0] + jr * 64 +
                              ((hi16 ^ ((jr >> 1) & 3)) << 4));
    }
#pragma unroll
    for (int m = 0; m < 4; m++)
#pragma unroll
      for (int n = 0; n < 8; n++)
        acc[m][n] = __builtin_amdgcn_mfma_f32_16x16x32_f16(af[m], bf[n], acc[m][n], 0, 0, 0);

    __builtin_amdgcn_s_barrier();   // all reads of buf[cur] done before restage
  }
#undef STAGE

  // ---- epilogue: Zh write + per-head el/er partials ----
  float bv[8], av[8], rv[8];
#pragma unroll
  for (int n = 0; n < 8; n++) {
    int j = wc * 128 + n * 16 + rl;
    bv[n] = bias[j]; av[n] = al[j]; rv[n] = ar[j];
  }

  float partl[4][4], partr[4][4];
#pragma unroll
  for (int m = 0; m < 4; m++)
#pragma unroll
    for (int qq = 0; qq < 4; qq++) { partl[m][qq] = 0.f; partr[m][qq] = 0.f; }

#pragma unroll
  for (int n = 0; n < 8; n++) {
    int j = wc * 128 + n * 16 + rl;
#pragma unroll
    for (int m = 0; m < 4; m++) {
      int rbase = n0 + wr * 64 + m * 16 + hi16 * 4;
#pragma unroll
      for (int qq = 0; qq < 4; qq++) {
        float v = acc[m][n][qq] + bv[n];
        int nrow = rbase + qq;
        if (nrow < N) Zh[(size_t)nrow * OH + j] = (half_t)v;
        partl[m][qq] = fmaf(v, av[n], partl[m][qq]);
        partr[m][qq] = fmaf(v, rv[n], partr[m][qq]);
      }
    }
  }
  const int h = rl & 7;
#pragma unroll
  for (int m = 0; m < 4; m++) {
#pragma unroll
    for (int qq = 0; qq < 4; qq++) {
      float pl = partl[m][qq], pr = partr[m][qq];
      pl += __shfl_xor(pl, 8);    // fold rl and rl+8 (same head)
      pr += __shfl_xor(pr, 8);
      if (rl < 8) {
        int nrow = n0 + wr * 64 + m * 16 + hi16 * 4 + qq;
        if (nrow < N) {
          atomicAdd(&el[(size_t)nrow * NH + h], pl);
          atomicAdd(&er[(size_t)nrow * NH + h], pr);
        }
      }
    }
  }
}

// ---------------------------------------------------------------------------
// CSR scans
// ---------------------------------------------------------------------------
#define SCAN_B 1024
__global__ __launch_bounds__(SCAN_B) void k_scan1(const int* __restrict__ deg,
                                                  int* __restrict__ off,
                                                  int* __restrict__ sums, int N) {
  __shared__ int s[SCAN_B];
  int tid = threadIdx.x;
  int g = blockIdx.x * SCAN_B + tid;
  int v = (g < N) ? deg[g] : 0;
  s[tid] = v;
  __syncthreads();
  for (int o = 1; o < SCAN_B; o <<= 1) {
    int t = (tid >= o) ? s[tid - o] : 0;
    __syncthreads();
    s[tid] += t;
    __syncthreads();
  }
  if (g < N) off[g] = s[tid] - v;
  if (tid == SCAN_B - 1) sums[blockIdx.x] = s[tid];
}

__global__ __launch_bounds__(SCAN_B) void k_scan3(int* __restrict__ off,
                                                  int* __restrict__ cursor,
                                                  const int* __restrict__ sums,
                                                  int nb, int N, int E) {
  __shared__ int sboff;
  int tid = threadIdx.x;
  if (tid < 64) {
    int v = (tid < nb && tid < (int)blockIdx.x) ? sums[tid] : 0;
#pragma unroll
    for (int s = 1; s < 64; s <<= 1) v += __shfl_xor(v, s);
    if (tid == 0) sboff = v;
  }
  __syncthreads();
  int g = blockIdx.x * SCAN_B + tid;
  if (g < N) {
    int v = off[g] + sboff;
    off[g] = v;
    cursor[g] = v;
  }
  if (g == 0) off[N] = E;
}

// ---------------------------------------------------------------------------
// Fused edge-softmax + aggregation (NT store for out, NT load for colS)
// ---------------------------------------------------------------------------
__global__ __launch_bounds__(256) void k_attagg(const half_t* __restrict__ Zh,
                                                const float* __restrict__ el,
                                                const float* __restrict__ er,
                                                const int* __restrict__ off,
                                                const int* __restrict__ colS,
                                                float* __restrict__ out, int N) {
  __shared__ float wts[4][64][NH];   // 8 KB
  __shared__ int   cls[4][64];       // 1 KB
  int wid = threadIdx.x >> 6, lane = threadIdx.x & 63;
  int i = blockIdx.x * 4 + wid;
  if (i >= N) return;
  int s = off[i], t = off[i + 1];
  int deg = t - s;

  float eli[8];
  {
    const float4* e4 = (const float4*)(el + (size_t)i * NH);
    float4 a = e4[0], b = e4[1];
    eli[0] = a.x; eli[1] = a.y; eli[2] = a.z; eli[3] = a.w;
    eli[4] = b.x; eli[5] = b.y; eli[6] = b.z; eli[7] = b.w;
  }

  float m[8], ehs[8];
  int csave = 0;
#pragma unroll
  for (int h = 0; h < 8; h++) m[h] = -1e30f;
  for (int p = s + lane; p < t; p += 64) {
    int c = __builtin_nontemporal_load(&colS[p]);
    csave = c;
    const float4* e4 = (const float4*)(er + (size_t)c * NH);
    float4 ea = e4[0], eb = e4[1];
    float ev[8] = {ea.x, ea.y, ea.z, ea.w, eb.x, eb.y, eb.z, eb.w};
#pragma unroll
    for (int h = 0; h < 8; h++) {
      float eh = eli[h] + ev[h];
      eh = (eh > 0.f) ? eh : 0.01f * eh;
      ehs[h] = eh;
      m[h] = fmaxf(m[h], eh);
    }
  }
#pragma unroll
  for (int st = 1; st < 64; st <<= 1)
#pragma unroll
    for (int h = 0; h < 8; h++) m[h] = fmaxf(m[h], __shfl_xor(m[h], st));

  float acc[8], den[8];
#pragma unroll
  for (int h = 0; h < 8; h++) { acc[h] = 0.f; den[h] = 0.f; }

  for (int base = s; base < t; base += 64) {
    int p = base + lane;
    if (p < t) {
      int c;
      float eh[8];
      if (deg <= 64) {
        c = csave;
#pragma unroll
        for (int h = 0; h < 8; h++) eh[h] = ehs[h];
      } else {
        c = __builtin_nontemporal_load(&colS[p]);
        const float4* e4 = (const float4*)(er + (size_t)c * NH);
        float4 ea = e4[0], eb = e4[1];
        float ev[8] = {ea.x, ea.y, ea.z, ea.w, eb.x, eb.y, eb.z, eb.w};
#pragma unroll
        for (int h = 0; h < 8; h++) {
          float e2 = eli[h] + ev[h];
          eh[h] = (e2 > 0.f) ? e2 : 0.01f * e2;
        }
      }
      cls[wid][lane] = c;
#pragma unroll
      for (int h = 0; h < 8; h++) {
        float pr = __expf(eh[h] - m[h]);
        den[h] += pr;
        wts[wid][lane][h] = pr;
      }
    }
    int cnt = t - base; if (cnt > 64) cnt = 64;

    int e = 0;
    for (; e + 4 <= cnt; e += 4) {
      int c0 = cls[wid][e + 0], c1 = cls[wid][e + 1];
      int c2 = cls[wid][e + 2], c3 = cls[wid][e + 3];
      f16x8 z0 = *(const f16x8*)(Zh + (size_t)c0 * OH + lane * 8);
      f16x8 z1 = *(const f16x8*)(Zh + (size_t)c1 * OH + lane * 8);
      f16x8 z2 = *(const f16x8*)(Zh + (size_t)c2 * OH + lane * 8);
      f16x8 z3 = *(const f16x8*)(Zh + (size_t)c3 * OH + lane * 8);
      const float* w0 = &wts[wid][e + 0][0];
      const float* w1 = &wts[wid][e + 1][0];
      const float* w2 = &wts[wid][e + 2][0];
      const float* w3 = &wts[wid][e + 3][0];
#pragma unroll
      for (int h = 0; h < 8; h++) {
        acc[h] = fmaf(w0[h], (float)z0[h], acc[h]);
        acc[h] = fmaf(w1[h], (float)z1[h], acc[h]);
        acc[h] = fmaf(w2[h], (float)z2[h], acc[h]);
        acc[h] = fmaf(w3[h], (float)z3[h], acc[h]);
      }
    }
    for (; e < cnt; e++) {
      int c = cls[wid][e];
      f16x8 z = *(const f16x8*)(Zh + (size_t)c * OH + lane * 8);
      const float* w = &wts[wid][e][0];
#pragma unroll
      for (int h = 0; h < 8; h++) acc[h] = fmaf(w[h], (float)z[h], acc[h]);
    }
  }

#pragma unroll
  for (int st = 1; st < 64; st <<= 1)
#pragma unroll
    for (int h = 0; h < 8; h++) den[h] += __shfl_xor(den[h], st);

  f32x4 o0, o1;
  o0[0] = acc[0] / den[0]; o0[1] = acc[1] / den[1];
  o0[2] = acc[2] / den[2]; o0[3] = acc[3] / den[3];
  o1[0] = acc[4] / den[4]; o1[1] = acc[5] / den[5];
  o1[2] = acc[6] / den[6]; o1[3] = acc[7] / den[7];
  __builtin_nontemporal_store(o0, (f32x4*)(out + (size_t)i * OH + lane * 8));
  __builtin_nontemporal_store(o1, (f32x4*)(out + (size_t)i * OH + lane * 8 + 4));
}

// ---------------------------------------------------------------------------
extern "C" void kernel_launch(void* const* d_in, const int* in_sizes, int n_in,
                              void* d_out, int out_size, void* d_ws, size_t ws_size,
                              hipStream_t stream) {
  const float* X    = (const float*)d_in[0];
  const float* W    = (const float*)d_in[1];
  const float* bias = (const float*)d_in[2];
  const float* a_l  = (const float*)d_in[3];
  const float* a_r  = (const float*)d_in[4];
  const int*   row  = (const int*)d_in[5];
  const int*   col  = (const int*)d_in[6];
  float* out = (float*)d_out;

  const int N = in_sizes[0] / IN_F;   // 50000
  const int E = in_sizes[5];          // 850000
  const int nWe = OH * IN_F;

  auto align_up = [](size_t v) { return (v + 255) & ~(size_t)255; };
  char* p = (char*)d_ws;
  half_t* Wh    = (half_t*)p; p += align_up((size_t)nWe * 2);
  half_t* Zh    = (half_t*)p; p += align_up((size_t)N * OH * 2);
  float* el     = (float*)p;  p += (size_t)N * NH * 4;        // el/er contiguous
  float* er     = (float*)p;  p += align_up((size_t)N * NH * 4);
  int*   deg    = (int*)p;    p += align_up((size_t)N * 4);
  int*   off    = (int*)p;    p += align_up((size_t)(N + 1) * 4);
  int*   cursor = (int*)p;    p += align_up((size_t)N * 4);
  int*   sums   = (int*)p;    p += align_up((size_t)64 * 4);
  int*   colS   = (int*)p;    p += align_up((size_t)E * 4);
  (void)ws_size; (void)n_in; (void)out_size;

  const int nb = (N + SCAN_B - 1) / SCAN_B;

  // deg must be zero before prep's histogram part
  hipMemsetAsync(deg, 0, (size_t)N * 4, stream);

  // prep: cast W + degree histogram + zero el/er
  const int nbW = (nWe / 8 + 255) / 256;
  const int nbH = (E + 255) / 256;
  const int nZ4 = 2 * N * NH / 4;
  const int nbZ = (nZ4 + 255) / 256;
  hipLaunchKernelGGL(k_prep, dim3(nbW + nbH + nbZ), dim3(256), 0, stream,
                     W, Wh, nWe, row, deg, E, el, nZ4, nbW, nbH);

  // CSR scans (need only deg)
  hipLaunchKernelGGL(k_scan1, dim3(nb), dim3(SCAN_B), 0, stream, deg, off, sums, N);
  hipLaunchKernelGGL(k_scan3, dim3(nb), dim3(SCAN_B), 0, stream,
                     off, cursor, sums, nb, N, E);

  // mega: GEMM (v7b) + CSR fill in one launch
  const int nwgG = (N + 127) / 128;              // 391 GEMM blocks
  const int nbF  = (E + 511) / 512;              // fill blocks
  hipLaunchKernelGGL(k_mega, dim3(nwgG + nbF), dim3(512), 0, stream,
                     X, Wh, bias, a_l, a_r, Zh, el, er, N, nwgG,
                     row, col, cursor, colS, E);

  // fused softmax + aggregation
  hipLaunchKernelGGL(k_attagg, dim3((N + 3) / 4), dim3(256), 0, stream,
                     Zh, el, er, off, colS, out, N);
}